// Round 7
// baseline (271.600 us; speedup 1.0000x reference)
//
#include <hip/hip_runtime.h>
#include <hip/hip_bf16.h>

// Problem constants (fixed by reference setup: N=4096, D=512, C=100)
#define D_DIM 512
#define KSTEPS 16          // 512 / 32 (K per MFMA)
#define BM 128             // row-indices per block = 4 waves x 32 (reuse-32)
#define BN 32              // columns per LDS tile (single buffer, 32 KB)
#define GRIDY 16           // column chunks -> 32*16 = 512 blocks = 2/CU, 8 waves/CU

typedef __bf16 bf16x8 __attribute__((ext_vector_type(8)));
typedef float  f32x4  __attribute__((ext_vector_type(4)));

__device__ __forceinline__ unsigned short f2bf_rne(float x) {
    unsigned int u = __float_as_uint(x);
    u += 0x7FFFu + ((u >> 16) & 1u);
    return (unsigned short)(u >> 16);
}

// async global->LDS, 16B per lane. Dest is wave-uniform base + lane*16 (HW rule).
__device__ __forceinline__ void g2l16(const void* g, void* l) {
    __builtin_amdgcn_global_load_lds(
        (const __attribute__((address_space(1))) unsigned int*)g,
        (__attribute__((address_space(3))) unsigned int*)l, 16, 0, 0);
}

// 512 blocks x 256 threads; each wave normalizes 4 rows (lane-parallel over D).
// rows [0,N): inst_embed -> instb ; rows [N,2N): proxy -> proxyb.
// Blocks 0..15 zero the nd accumulator; block 16 zeroes the done-counter.
__global__ __launch_bounds__(256) void normalize_rows(
    const float* __restrict__ inst, const float* __restrict__ proxy,
    unsigned short* __restrict__ instb, unsigned short* __restrict__ proxyb,
    float* __restrict__ nd, int* __restrict__ ctr, int N)
{
    const int lane = threadIdx.x & 63;
    const int wave = threadIdx.x >> 6;
    const int base = blockIdx.x * 16 + wave * 4;
    #pragma unroll
    for (int i = 0; i < 4; ++i) {
        const int row = base + i;
        const float* src;
        unsigned short* dst;
        if (row < N) { src = inst  + (size_t)row * D_DIM;        dst = instb  + (size_t)row * D_DIM; }
        else         { src = proxy + (size_t)(row - N) * D_DIM;  dst = proxyb + (size_t)(row - N) * D_DIM; }
        float4 v0 = ((const float4*)src)[lane * 2];
        float4 v1 = ((const float4*)src)[lane * 2 + 1];
        float ss = v0.x*v0.x + v0.y*v0.y + v0.z*v0.z + v0.w*v0.w
                 + v1.x*v1.x + v1.y*v1.y + v1.z*v1.z + v1.w*v1.w;
        #pragma unroll
        for (int off = 32; off > 0; off >>= 1) ss += __shfl_xor(ss, off, 64);
        const float inv = 1.0f / fmaxf(sqrtf(ss), 1e-8f);
        ushort4 o0, o1;
        o0.x = f2bf_rne(v0.x * inv); o0.y = f2bf_rne(v0.y * inv);
        o0.z = f2bf_rne(v0.z * inv); o0.w = f2bf_rne(v0.w * inv);
        o1.x = f2bf_rne(v1.x * inv); o1.y = f2bf_rne(v1.y * inv);
        o1.z = f2bf_rne(v1.z * inv); o1.w = f2bf_rne(v1.w * inv);
        ((ushort4*)dst)[lane * 2]     = o0;
        ((ushort4*)dst)[lane * 2 + 1] = o1;
    }
    if (blockIdx.x < 16)   // 16 blocks x 256 threads x 16B = 16384 floats = 4N
        ((float4*)nd)[blockIdx.x * 256 + threadIdx.x] = make_float4(0.f, 0.f, 0.f, 0.f);
    if (blockIdx.x == 16 && threadIdx.x == 0) *ctr = 0;
}

// Reuse-32 fused kernel (r4-verified core) at r2-verified occupancy:
// per block 128 row-indices; each wave owns 32 indices x BOTH matrices
// (4 A-slabs ~240 regs, AGPR-backed). Every B fragment from LDS feeds 4 MFMAs.
// 512 blocks = 2/CU (32 KB LDS each), 8 waves/CU. r1-proven 2-barrier tile loop.
// Last finishing block performs the loss reduction (agent-scope loads).
// nd layout: [p2i_num | p2i_den | i2i_num | i2i_den], each N floats, pre-zeroed.
__global__ __launch_bounds__(256, 2) void fused_scores(
    const unsigned short* __restrict__ instb,
    const unsigned short* __restrict__ proxyb,
    const float* __restrict__ negmask,   // [C, N]
    const int*  __restrict__ labels,     // [N]
    const float* __restrict__ temp_p,
    const float* __restrict__ margin_p,
    float* __restrict__ nd,
    int* __restrict__ ctr,
    float* __restrict__ out,
    int N, int colsPerBlock)
{
    __shared__ unsigned short Bt[BN * D_DIM];   // 32 KB, xor-swizzled 16B chunks

    const int tid  = threadIdx.x;
    const int lane = tid & 63;
    const int wave = tid >> 6;      // 0..3
    const int quad = lane >> 4;     // 0..3
    const int l16  = lane & 15;

    // Column chunk -> XCD partition: wgid%8 == XCD (round-robin dispatch).
    // by = wgid & 15: chunks c and c+8 share XCD c%8 -> 2 panels (512 KB) per L2.
    const int bx = blockIdx.x >> 4;
    const int by = blockIdx.x & 15;

    const int row0   = bx * BM + wave * 32;      // wave's 32 row-indices
    const int j0base = by * colsPerBlock;

    const float temp  = *temp_p;
    const float scale = 1.44269504088896340736f / temp;   // log2(e)/t
    const float bias  = -(*margin_p) * scale;

    // Four A slabs resident in registers: MFMA A-layout A[m=lane&15][k=quad*8+j]
    // group 0 = rows row0..+15, group 1 = rows row0+16..+31
    bf16x8 Ap0[KSTEPS], Ai0[KSTEPS], Ap1[KSTEPS], Ai1[KSTEPS];
    {
        const unsigned short* p0 = proxyb + (size_t)(row0 + l16)      * D_DIM + quad * 8;
        const unsigned short* i0 = instb  + (size_t)(row0 + l16)      * D_DIM + quad * 8;
        const unsigned short* p1 = proxyb + (size_t)(row0 + 16 + l16) * D_DIM + quad * 8;
        const unsigned short* i1 = instb  + (size_t)(row0 + 16 + l16) * D_DIM + quad * 8;
        #pragma unroll
        for (int ks = 0; ks < KSTEPS; ks++) {
            Ap0[ks] = *(const bf16x8*)(p0 + ks * 32);
            Ai0[ks] = *(const bf16x8*)(i0 + ks * 32);
            Ap1[ks] = *(const bf16x8*)(p1 + ks * 32);
            Ai1[ks] = *(const bf16x8*)(i1 + ks * 32);
        }
    }

    // labels for this lane's output rows (C/D layout: row = quad*4 + r), per group
    int lab[2][4];
    #pragma unroll
    for (int g = 0; g < 2; g++)
        #pragma unroll
        for (int r = 0; r < 4; r++)
            lab[g][r] = labels[row0 + g * 16 + quad * 4 + r];

    float numP[2][4] = {}, denP[2][4] = {};
    float numI[2][4] = {}, denI[2][4] = {};

    for (int jt = 0; jt < colsPerBlock; jt += BN) {
        const int j0 = j0base + jt;
        __syncthreads();   // protect previous tile's reads before overwrite
        // Stage B tile: 32 rows x 512 bf16 via g2l16; LDS dest linear per row,
        // xor-swizzle on the SOURCE 16B-chunk index (both-sides involution).
        #pragma unroll
        for (int it = 0; it < BN / 4; it++) {
            const int br = it * 4 + wave;        // wave-uniform row in tile
            const unsigned short* src =
                instb + (size_t)(j0 + br) * D_DIM + ((lane ^ (br & 7)) * 8);
            g2l16(src, &Bt[(size_t)br * D_DIM]);
        }
        __syncthreads();   // vmcnt(0) drain + barrier: tile ready

        // Prefetch masks: 16 independent gathers hide under the MFMA cluster
        float mk[2][2][4];
        #pragma unroll
        for (int g = 0; g < 2; ++g)
            #pragma unroll
            for (int c = 0; c < 2; ++c)
                #pragma unroll
                for (int r = 0; r < 4; ++r)
                    mk[g][c][r] = negmask[(size_t)lab[g][r] * N + (j0 + c * 16 + l16)];

        f32x4 aP0[2] = {}, aI0[2] = {}, aP1[2] = {}, aI1[2] = {};
        __builtin_amdgcn_s_setprio(1);
        #pragma unroll
        for (int ks = 0; ks < KSTEPS; ++ks) {
            #pragma unroll
            for (int cg = 0; cg < 2; ++cg) {
                const int rB  = cg * 16 + l16;               // B column = LDS row
                const int chs = (ks * 4 + quad) ^ (rB & 7);
                bf16x8 b = *(const bf16x8*)&Bt[(size_t)rB * D_DIM + chs * 8];
                aP0[cg] = __builtin_amdgcn_mfma_f32_16x16x32_bf16(Ap0[ks], b, aP0[cg], 0, 0, 0);
                aI0[cg] = __builtin_amdgcn_mfma_f32_16x16x32_bf16(Ai0[ks], b, aI0[cg], 0, 0, 0);
                aP1[cg] = __builtin_amdgcn_mfma_f32_16x16x32_bf16(Ap1[ks], b, aP1[cg], 0, 0, 0);
                aI1[cg] = __builtin_amdgcn_mfma_f32_16x16x32_bf16(Ai1[ks], b, aI1[cg], 0, 0, 0);
            }
        }
        __builtin_amdgcn_s_setprio(0);

        // Epilogue: zone = exp2(sim*scale + bias); one mask value feeds P and I
        #pragma unroll
        for (int cg = 0; cg < 2; ++cg) {
            #pragma unroll
            for (int r = 0; r < 4; ++r) {
                float zp0 = exp2f(aP0[cg][r] * scale + bias);
                float zi0 = exp2f(aI0[cg][r] * scale + bias);
                float zp1 = exp2f(aP1[cg][r] * scale + bias);
                float zi1 = exp2f(aI1[cg][r] * scale + bias);
                denP[0][r] += zp0; numP[0][r] += zp0 * mk[0][cg][r];
                denI[0][r] += zi0; numI[0][r] += zi0 * mk[0][cg][r];
                denP[1][r] += zp1; numP[1][r] += zp1 * mk[1][cg][r];
                denI[1][r] += zi1; numI[1][r] += zi1 * mk[1][cg][r];
            }
        }
    }

    // Reduce across the 16 lanes (l16) sharing each output row, then atomicAdd
    #pragma unroll
    for (int g = 0; g < 2; ++g) {
        #pragma unroll
        for (int r = 0; r < 4; ++r) {
            float np = numP[g][r], dp = denP[g][r], ni = numI[g][r], di = denI[g][r];
            #pragma unroll
            for (int off = 8; off > 0; off >>= 1) {
                np += __shfl_down(np, off, 16);
                dp += __shfl_down(dp, off, 16);
                ni += __shfl_down(ni, off, 16);
                di += __shfl_down(di, off, 16);
            }
            if (l16 == 0) {
                const int row = row0 + g * 16 + quad * 4 + r;
                atomicAdd(&nd[row],         np);
                atomicAdd(&nd[N + row],     dp);
                atomicAdd(&nd[2 * N + row], ni);
                atomicAdd(&nd[3 * N + row], di);
            }
        }
    }

    // ---- Last-block-done loss reduction (replaces the loss_reduce dispatch) ----
    __shared__ int isLast;
    __threadfence();                         // release this block's atomics
    if (tid == 0) {
        int prev = __hip_atomic_fetch_add(ctr, 1, __ATOMIC_ACQ_REL,
                                          __HIP_MEMORY_SCOPE_AGENT);
        isLast = (prev == (int)gridDim.x - 1);
    }
    __syncthreads();
    if (isLast) {
        // All blocks' atomics happen-before the winning fetch_add. Read nd with
        // agent-scope atomic loads (per-XCD L2s are not coherent for plain loads).
        float s = 0.f;
        for (int i = tid; i < N; i += 256) {
            float pn = __hip_atomic_load(&nd[i],         __ATOMIC_RELAXED, __HIP_MEMORY_SCOPE_AGENT);
            float pd = __hip_atomic_load(&nd[N + i],     __ATOMIC_RELAXED, __HIP_MEMORY_SCOPE_AGENT);
            float in_ = __hip_atomic_load(&nd[2 * N + i], __ATOMIC_RELAXED, __HIP_MEMORY_SCOPE_AGENT);
            float id = __hip_atomic_load(&nd[3 * N + i], __ATOMIC_RELAXED, __HIP_MEMORY_SCOPE_AGENT);
            s += (logf(pd) - logf(pn)) + (logf(id) - logf(in_));
        }
        #pragma unroll
        for (int off = 32; off > 0; off >>= 1) s += __shfl_down(s, off, 64);
        float* wss = (float*)Bt;             // LDS reuse; compute phase done
        __syncthreads();
        if ((tid & 63) == 0) wss[tid >> 6] = s;
        __syncthreads();
        if (tid == 0)
            out[0] = (wss[0] + wss[1] + wss[2] + wss[3]) / (float)N
                   - 2.0f * logf(temp);
    }
}

extern "C" void kernel_launch(void* const* d_in, const int* in_sizes, int n_in,
                              void* d_out, int out_size, void* d_ws, size_t ws_size,
                              hipStream_t stream)
{
    const float* inst     = (const float*)d_in[0];
    const float* proxy    = (const float*)d_in[1];
    const float* negmask  = (const float*)d_in[2];
    const int*   labels   = (const int*)d_in[3];
    const float* temp_p   = (const float*)d_in[4];
    const float* margin_p = (const float*)d_in[5];
    float* out = (float*)d_out;

    const int N = in_sizes[3];    // 4096 (D fixed at 512 per reference)

    unsigned short* instb  = (unsigned short*)d_ws;
    unsigned short* proxyb = instb + (size_t)N * D_DIM;
    float* nd = (float*)(proxyb + (size_t)N * D_DIM);
    int*  ctr = (int*)(nd + 4 * (size_t)N);

    normalize_rows<<<2 * N / 16, 256, 0, stream>>>(inst, proxy, instb, proxyb,
                                                   nd, ctr, N);
    fused_scores<<<(N / BM) * GRIDY, 256, 0, stream>>>(instb, proxyb, negmask,
                                                       labels, temp_p, margin_p,
                                                       nd, ctr, out, N, N / GRIDY);
}

// Round 8
// 182.227 us; speedup vs baseline: 1.4905x; 1.4905x over previous
//
#include <hip/hip_runtime.h>
#include <hip/hip_bf16.h>

// Problem constants (fixed by reference setup: N=4096, D=512, C=100)
#define D_DIM 512
#define KSTEPS 16          // 512 / 32 (K per MFMA)
#define BM 128             // row-indices per block = 4 waves x 32 (reuse-32)
#define BN 32              // columns per LDS tile (single buffer, 32 KB)
#define GRIDY 16           // column chunks -> 32*16 = 512 blocks = 2/CU, 8 waves/CU

typedef __bf16 bf16x8 __attribute__((ext_vector_type(8)));
typedef float  f32x4  __attribute__((ext_vector_type(4)));

__device__ __forceinline__ unsigned short f2bf_rne(float x) {
    unsigned int u = __float_as_uint(x);
    u += 0x7FFFu + ((u >> 16) & 1u);
    return (unsigned short)(u >> 16);
}

// async global->LDS, 16B per lane. Dest is wave-uniform base + lane*16 (HW rule).
__device__ __forceinline__ void g2l16(const void* g, void* l) {
    __builtin_amdgcn_global_load_lds(
        (const __attribute__((address_space(1))) unsigned int*)g,
        (__attribute__((address_space(3))) unsigned int*)l, 16, 0, 0);
}

// 512 blocks x 256 threads; each wave normalizes 4 rows (lane-parallel over D).
// rows [0,N): inst_embed -> instb ; rows [N,2N): proxy -> proxyb.
// Blocks 0..15 zero the nd accumulator; block 16 zeroes the done-counter.
__global__ __launch_bounds__(256) void normalize_rows(
    const float* __restrict__ inst, const float* __restrict__ proxy,
    unsigned short* __restrict__ instb, unsigned short* __restrict__ proxyb,
    float* __restrict__ nd, int* __restrict__ ctr, int N)
{
    const int lane = threadIdx.x & 63;
    const int wave = threadIdx.x >> 6;
    const int base = blockIdx.x * 16 + wave * 4;
    #pragma unroll
    for (int i = 0; i < 4; ++i) {
        const int row = base + i;
        const float* src;
        unsigned short* dst;
        if (row < N) { src = inst  + (size_t)row * D_DIM;        dst = instb  + (size_t)row * D_DIM; }
        else         { src = proxy + (size_t)(row - N) * D_DIM;  dst = proxyb + (size_t)(row - N) * D_DIM; }
        float4 v0 = ((const float4*)src)[lane * 2];
        float4 v1 = ((const float4*)src)[lane * 2 + 1];
        float ss = v0.x*v0.x + v0.y*v0.y + v0.z*v0.z + v0.w*v0.w
                 + v1.x*v1.x + v1.y*v1.y + v1.z*v1.z + v1.w*v1.w;
        #pragma unroll
        for (int off = 32; off > 0; off >>= 1) ss += __shfl_xor(ss, off, 64);
        const float inv = 1.0f / fmaxf(sqrtf(ss), 1e-8f);
        ushort4 o0, o1;
        o0.x = f2bf_rne(v0.x * inv); o0.y = f2bf_rne(v0.y * inv);
        o0.z = f2bf_rne(v0.z * inv); o0.w = f2bf_rne(v0.w * inv);
        o1.x = f2bf_rne(v1.x * inv); o1.y = f2bf_rne(v1.y * inv);
        o1.z = f2bf_rne(v1.z * inv); o1.w = f2bf_rne(v1.w * inv);
        ((ushort4*)dst)[lane * 2]     = o0;
        ((ushort4*)dst)[lane * 2 + 1] = o1;
    }
    if (blockIdx.x < 16)   // 16 blocks x 256 threads x 16B = 16384 floats = 4N
        ((float4*)nd)[blockIdx.x * 256 + threadIdx.x] = make_float4(0.f, 0.f, 0.f, 0.f);
    if (blockIdx.x == 16 && threadIdx.x == 0) *ctr = 0;
}

// Reuse-32 fused kernel. Per block 128 row-indices; each wave owns 32 indices x
// BOTH matrices (4 A-slabs ~240 regs, AGPR-backed; every B fragment from LDS
// feeds 4 MFMAs). 512 blocks, 32 KB LDS -> HW fits 2 blocks/CU at 240 regs
// (2 waves/SIMD). CRITICAL: __launch_bounds__(256, 1) — min-waves=1 is the ONLY
// setting where the allocator grants slab residency (r4: 240 VGPR, no spill);
// min-waves=2 made it target 128 VGPR and spill all slabs (r7: 85 MB scratch).
// Last finishing block performs the loss reduction (agent-scope loads).
// nd layout: [p2i_num | p2i_den | i2i_num | i2i_den], each N floats, pre-zeroed.
__global__ __launch_bounds__(256, 1) void fused_scores(
    const unsigned short* __restrict__ instb,
    const unsigned short* __restrict__ proxyb,
    const float* __restrict__ negmask,   // [C, N]
    const int*  __restrict__ labels,     // [N]
    const float* __restrict__ temp_p,
    const float* __restrict__ margin_p,
    float* __restrict__ nd,
    int* __restrict__ ctr,
    float* __restrict__ out,
    int N, int colsPerBlock)
{
    __shared__ unsigned short Bt[BN * D_DIM];   // 32 KB, xor-swizzled 16B chunks

    const int tid  = threadIdx.x;
    const int lane = tid & 63;
    const int wave = tid >> 6;      // 0..3
    const int quad = lane >> 4;     // 0..3
    const int l16  = lane & 15;

    // Column chunk -> XCD partition: wgid%8 == XCD (round-robin dispatch).
    // by = wgid & 15: chunks c and c+8 share XCD c%8 -> 2 panels (512 KB) per L2.
    const int bx = blockIdx.x >> 4;
    const int by = blockIdx.x & 15;

    const int row0   = bx * BM + wave * 32;      // wave's 32 row-indices
    const int j0base = by * colsPerBlock;

    const float temp  = *temp_p;
    const float scale = 1.44269504088896340736f / temp;   // log2(e)/t
    const float bias  = -(*margin_p) * scale;

    // Four A slabs resident in registers: MFMA A-layout A[m=lane&15][k=quad*8+j]
    // group 0 = rows row0..+15, group 1 = rows row0+16..+31
    bf16x8 Ap0[KSTEPS], Ai0[KSTEPS], Ap1[KSTEPS], Ai1[KSTEPS];
    {
        const unsigned short* p0 = proxyb + (size_t)(row0 + l16)      * D_DIM + quad * 8;
        const unsigned short* i0 = instb  + (size_t)(row0 + l16)      * D_DIM + quad * 8;
        const unsigned short* p1 = proxyb + (size_t)(row0 + 16 + l16) * D_DIM + quad * 8;
        const unsigned short* i1 = instb  + (size_t)(row0 + 16 + l16) * D_DIM + quad * 8;
        #pragma unroll
        for (int ks = 0; ks < KSTEPS; ks++) {
            Ap0[ks] = *(const bf16x8*)(p0 + ks * 32);
            Ai0[ks] = *(const bf16x8*)(i0 + ks * 32);
            Ap1[ks] = *(const bf16x8*)(p1 + ks * 32);
            Ai1[ks] = *(const bf16x8*)(i1 + ks * 32);
        }
    }

    // labels for this lane's output rows (C/D layout: row = quad*4 + r), per group
    int lab[2][4];
    #pragma unroll
    for (int g = 0; g < 2; g++)
        #pragma unroll
        for (int r = 0; r < 4; r++)
            lab[g][r] = labels[row0 + g * 16 + quad * 4 + r];

    float numP[2][4] = {}, denP[2][4] = {};
    float numI[2][4] = {}, denI[2][4] = {};

    for (int jt = 0; jt < colsPerBlock; jt += BN) {
        const int j0 = j0base + jt;
        __syncthreads();   // protect previous tile's reads before overwrite
        // Stage B tile: 32 rows x 512 bf16 via g2l16; LDS dest linear per row,
        // xor-swizzle on the SOURCE 16B-chunk index (both-sides involution).
        #pragma unroll
        for (int it = 0; it < BN / 4; it++) {
            const int br = it * 4 + wave;        // wave-uniform row in tile
            const unsigned short* src =
                instb + (size_t)(j0 + br) * D_DIM + ((lane ^ (br & 7)) * 8);
            g2l16(src, &Bt[(size_t)br * D_DIM]);
        }
        __syncthreads();   // vmcnt(0) drain + barrier: tile ready

        // Prefetch masks: 16 independent gathers hide under the MFMA cluster
        float mk[2][2][4];
        #pragma unroll
        for (int g = 0; g < 2; ++g)
            #pragma unroll
            for (int c = 0; c < 2; ++c)
                #pragma unroll
                for (int r = 0; r < 4; ++r)
                    mk[g][c][r] = negmask[(size_t)lab[g][r] * N + (j0 + c * 16 + l16)];

        f32x4 aP0[2] = {}, aI0[2] = {}, aP1[2] = {}, aI1[2] = {};
        __builtin_amdgcn_s_setprio(1);
        #pragma unroll
        for (int ks = 0; ks < KSTEPS; ++ks) {
            #pragma unroll
            for (int cg = 0; cg < 2; ++cg) {
                const int rB  = cg * 16 + l16;               // B column = LDS row
                const int chs = (ks * 4 + quad) ^ (rB & 7);
                bf16x8 b = *(const bf16x8*)&Bt[(size_t)rB * D_DIM + chs * 8];
                aP0[cg] = __builtin_amdgcn_mfma_f32_16x16x32_bf16(Ap0[ks], b, aP0[cg], 0, 0, 0);
                aI0[cg] = __builtin_amdgcn_mfma_f32_16x16x32_bf16(Ai0[ks], b, aI0[cg], 0, 0, 0);
                aP1[cg] = __builtin_amdgcn_mfma_f32_16x16x32_bf16(Ap1[ks], b, aP1[cg], 0, 0, 0);
                aI1[cg] = __builtin_amdgcn_mfma_f32_16x16x32_bf16(Ai1[ks], b, aI1[cg], 0, 0, 0);
            }
        }
        __builtin_amdgcn_s_setprio(0);

        // Epilogue: zone = exp2(sim*scale + bias); one mask value feeds P and I
        #pragma unroll
        for (int cg = 0; cg < 2; ++cg) {
            #pragma unroll
            for (int r = 0; r < 4; ++r) {
                float zp0 = exp2f(aP0[cg][r] * scale + bias);
                float zi0 = exp2f(aI0[cg][r] * scale + bias);
                float zp1 = exp2f(aP1[cg][r] * scale + bias);
                float zi1 = exp2f(aI1[cg][r] * scale + bias);
                denP[0][r] += zp0; numP[0][r] += zp0 * mk[0][cg][r];
                denI[0][r] += zi0; numI[0][r] += zi0 * mk[0][cg][r];
                denP[1][r] += zp1; numP[1][r] += zp1 * mk[1][cg][r];
                denI[1][r] += zi1; numI[1][r] += zi1 * mk[1][cg][r];
            }
        }
    }

    // Reduce across the 16 lanes (l16) sharing each output row, then atomicAdd
    #pragma unroll
    for (int g = 0; g < 2; ++g) {
        #pragma unroll
        for (int r = 0; r < 4; ++r) {
            float np = numP[g][r], dp = denP[g][r], ni = numI[g][r], di = denI[g][r];
            #pragma unroll
            for (int off = 8; off > 0; off >>= 1) {
                np += __shfl_down(np, off, 16);
                dp += __shfl_down(dp, off, 16);
                ni += __shfl_down(ni, off, 16);
                di += __shfl_down(di, off, 16);
            }
            if (l16 == 0) {
                const int row = row0 + g * 16 + quad * 4 + r;
                atomicAdd(&nd[row],         np);
                atomicAdd(&nd[N + row],     dp);
                atomicAdd(&nd[2 * N + row], ni);
                atomicAdd(&nd[3 * N + row], di);
            }
        }
    }

    // ---- Last-block-done loss reduction (replaces the loss_reduce dispatch) ----
    __shared__ int isLast;
    __threadfence();                         // release this block's atomics
    if (tid == 0) {
        int prev = __hip_atomic_fetch_add(ctr, 1, __ATOMIC_ACQ_REL,
                                          __HIP_MEMORY_SCOPE_AGENT);
        isLast = (prev == (int)gridDim.x - 1);
    }
    __syncthreads();
    if (isLast) {
        // All blocks' atomics happen-before the winning fetch_add. Read nd with
        // agent-scope atomic loads (per-XCD L2s are not coherent for plain loads).
        float s = 0.f;
        for (int i = tid; i < N; i += 256) {
            float pn  = __hip_atomic_load(&nd[i],         __ATOMIC_RELAXED, __HIP_MEMORY_SCOPE_AGENT);
            float pd  = __hip_atomic_load(&nd[N + i],     __ATOMIC_RELAXED, __HIP_MEMORY_SCOPE_AGENT);
            float in_ = __hip_atomic_load(&nd[2 * N + i], __ATOMIC_RELAXED, __HIP_MEMORY_SCOPE_AGENT);
            float id  = __hip_atomic_load(&nd[3 * N + i], __ATOMIC_RELAXED, __HIP_MEMORY_SCOPE_AGENT);
            s += (logf(pd) - logf(pn)) + (logf(id) - logf(in_));
        }
        #pragma unroll
        for (int off = 32; off > 0; off >>= 1) s += __shfl_down(s, off, 64);
        float* wss = (float*)Bt;             // LDS reuse; compute phase done
        __syncthreads();
        if ((tid & 63) == 0) wss[tid >> 6] = s;
        __syncthreads();
        if (tid == 0)
            out[0] = (wss[0] + wss[1] + wss[2] + wss[3]) / (float)N
                   - 2.0f * logf(temp);
    }
}

extern "C" void kernel_launch(void* const* d_in, const int* in_sizes, int n_in,
                              void* d_out, int out_size, void* d_ws, size_t ws_size,
                              hipStream_t stream)
{
    const float* inst     = (const float*)d_in[0];
    const float* proxy    = (const float*)d_in[1];
    const float* negmask  = (const float*)d_in[2];
    const int*   labels   = (const int*)d_in[3];
    const float* temp_p   = (const float*)d_in[4];
    const float* margin_p = (const float*)d_in[5];
    float* out = (float*)d_out;

    const int N = in_sizes[3];    // 4096 (D fixed at 512 per reference)

    unsigned short* instb  = (unsigned short*)d_ws;
    unsigned short* proxyb = instb + (size_t)N * D_DIM;
    float* nd = (float*)(proxyb + (size_t)N * D_DIM);
    int*  ctr = (int*)(nd + 4 * (size_t)N);

    normalize_rows<<<2 * N / 16, 256, 0, stream>>>(inst, proxy, instb, proxyb,
                                                   nd, ctr, N);
    fused_scores<<<(N / BM) * GRIDY, 256, 0, stream>>>(instb, proxyb, negmask,
                                                       labels, temp_p, margin_p,
                                                       nd, ctr, out, N, N / GRIDY);
}

// Round 9
// 151.103 us; speedup vs baseline: 1.7975x; 1.2060x over previous
//
#include <hip/hip_runtime.h>
#include <hip/hip_bf16.h>

// Problem constants (fixed by reference setup: N=4096, D=512, C=100)
#define D_DIM 512
#define KSTEPS 16          // 512 / 32 (K per fp8 MFMA)
#define BM 64              // row-indices per block (shared by p2i AND i2i)
#define BN 64              // columns per LDS tile (fp8 -> 32 KB, single buffer)
#define GRIDY 8            // column chunks -> 64*8 = 512 blocks = 2/CU
#define SCALE_Q 4.0f       // pre-quantization gain; sim scales by SCALE_Q^2

typedef long   f8x8;       // 8 fp8 in 2 VGPRs (MFMA A/B operand)
typedef float  f32x4  __attribute__((ext_vector_type(4)));

// async global->LDS, 16B per lane. Dest is wave-uniform base + lane*16 (HW rule).
__device__ __forceinline__ void g2l16(const void* g, void* l) {
    __builtin_amdgcn_global_load_lds(
        (const __attribute__((address_space(1))) unsigned int*)g,
        (__attribute__((address_space(3))) unsigned int*)l, 16, 0, 0);
}

// 512 blocks x 256 threads; each wave normalizes 4 rows (lane-parallel over D),
// quantizing to OCP fp8 e4m3 with gain SCALE_Q (elements ~0.18 std -> normal
// range, rel err 2^-4; sim error ~2e-3 << 0.13 threshold).
// rows [0,N): inst_embed -> instq ; rows [N,2N): proxy -> proxyq.
// Blocks 0..15 zero the nd accumulator; block 16 zeroes the done-counter.
__global__ __launch_bounds__(256) void normalize_rows(
    const float* __restrict__ inst, const float* __restrict__ proxy,
    unsigned char* __restrict__ instq, unsigned char* __restrict__ proxyq,
    float* __restrict__ nd, int* __restrict__ ctr, int N)
{
    const int lane = threadIdx.x & 63;
    const int wave = threadIdx.x >> 6;
    const int base = blockIdx.x * 16 + wave * 4;
    #pragma unroll
    for (int i = 0; i < 4; ++i) {
        const int row = base + i;
        const float* src;
        unsigned char* dst;
        if (row < N) { src = inst  + (size_t)row * D_DIM;        dst = instq  + (size_t)row * D_DIM; }
        else         { src = proxy + (size_t)(row - N) * D_DIM;  dst = proxyq + (size_t)(row - N) * D_DIM; }
        float4 v0 = ((const float4*)src)[lane * 2];
        float4 v1 = ((const float4*)src)[lane * 2 + 1];
        float ss = v0.x*v0.x + v0.y*v0.y + v0.z*v0.z + v0.w*v0.w
                 + v1.x*v1.x + v1.y*v1.y + v1.z*v1.z + v1.w*v1.w;
        #pragma unroll
        for (int off = 32; off > 0; off >>= 1) ss += __shfl_xor(ss, off, 64);
        const float inv = SCALE_Q / fmaxf(sqrtf(ss), 1e-8f);
        unsigned int w0 = 0, w1 = 0;
        w0 = __builtin_amdgcn_cvt_pk_fp8_f32(v0.x * inv, v0.y * inv, w0, false);
        w0 = __builtin_amdgcn_cvt_pk_fp8_f32(v0.z * inv, v0.w * inv, w0, true);
        w1 = __builtin_amdgcn_cvt_pk_fp8_f32(v1.x * inv, v1.y * inv, w1, false);
        w1 = __builtin_amdgcn_cvt_pk_fp8_f32(v1.z * inv, v1.w * inv, w1, true);
        ((uint2*)dst)[lane] = make_uint2(w0, w1);   // 8 fp8 per lane
    }
    if (blockIdx.x < 16)   // 16 blocks x 256 threads x 16B = 16384 floats = 4N
        ((float4*)nd)[blockIdx.x * 256 + threadIdx.x] = make_float4(0.f, 0.f, 0.f, 0.f);
    if (blockIdx.x == 16 && threadIdx.x == 0) *ctr = 0;
}

// fp8 fused kernel, r1-proven skeleton: per block 64 row-indices; both
// similarity matrices against the same staged B tile (each B fragment feeds 2
// MFMAs). fp8 halves LDS bytes/FLOP and A-slab registers vs bf16 (~190 regs ->
// 2 waves/SIMD, 8 waves/CU at 32 KB LDS). Single-buffer 2-barrier tile loop.
// Last finishing block performs the loss reduction (agent-scope loads).
// nd layout: [p2i_num | p2i_den | i2i_num | i2i_den], each N floats, pre-zeroed.
__global__ __launch_bounds__(256, 1) void fused_scores(
    const unsigned char* __restrict__ instq,
    const unsigned char* __restrict__ proxyq,
    const float* __restrict__ negmask,   // [C, N]
    const int*  __restrict__ labels,     // [N]
    const float* __restrict__ temp_p,
    const float* __restrict__ margin_p,
    float* __restrict__ nd,
    int* __restrict__ ctr,
    float* __restrict__ out,
    int N, int colsPerBlock)
{
    __shared__ unsigned char Bt[BN * D_DIM];   // 32 KB fp8, granule-swizzled

    const int tid  = threadIdx.x;
    const int lane = tid & 63;
    const int wave = tid >> 6;      // 0..3
    const int quad = lane >> 4;     // 0..3
    const int l16  = lane & 15;

    // Column chunk -> XCD partition: wgid%8 == XCD (round-robin dispatch);
    // all 64 blocks of one chunk on one XCD -> 256 KB B panel is L2-local.
    const int bx = blockIdx.x >> 3;
    const int by = blockIdx.x & 7;

    const int row0   = bx * BM + wave * 16;      // wave's 16 row-indices
    const int j0base = by * colsPerBlock;

    const float temp  = *temp_p;
    // acc = SCALE_Q^2 * sim ; zone = exp2(acc*scale + bias)
    const float scale = 1.44269504088896340736f / (temp * SCALE_Q * SCALE_Q);
    const float bias  = -(*margin_p) * 1.44269504088896340736f / temp;

    // Two A slabs resident in regs: fp8 A-layout A[m=lane&15][k=quad*8+j],
    // 8 fp8 = one long per k-step. 2 x 16 longs = 64 VGPRs total.
    f8x8 Ap[KSTEPS], Ai[KSTEPS];
    {
        const unsigned char* pr = proxyq + (size_t)(row0 + l16) * D_DIM + quad * 8;
        const unsigned char* ir = instq  + (size_t)(row0 + l16) * D_DIM + quad * 8;
        #pragma unroll
        for (int ks = 0; ks < KSTEPS; ks++) {
            Ap[ks] = *(const f8x8*)(pr + ks * 32);
            Ai[ks] = *(const f8x8*)(ir + ks * 32);
        }
    }

    // labels for this lane's 4 output rows (C/D layout: row = quad*4 + r)
    int lab[4];
    #pragma unroll
    for (int r = 0; r < 4; r++) lab[r] = labels[row0 + quad * 4 + r];

    float numP[4] = {0.f,0.f,0.f,0.f}, denP[4] = {0.f,0.f,0.f,0.f};
    float numI[4] = {0.f,0.f,0.f,0.f}, denI[4] = {0.f,0.f,0.f,0.f};

    for (int jt = 0; jt < colsPerBlock; jt += BN) {
        const int j0 = j0base + jt;
        __syncthreads();   // protect previous tile's reads before overwrite
        // Stage B tile: 64 rows x 512 B fp8. One g2l16 = 1024 B = 2 rows.
        // LDS dest linear; 16B-chunk xor-swizzle applied to the SOURCE index
        // (involution; read side XORs granules with ((row&7)<<1), see below).
        #pragma unroll
        for (int it = 0; it < 8; ++it) {
            const int rb = it * 8 + wave * 2 + (lane >> 5);   // row in tile
            const unsigned char* src =
                instq + (size_t)(j0 + rb) * D_DIM + (((lane & 31) ^ (rb & 7)) * 16);
            g2l16(src, &Bt[(size_t)(it * 8 + wave * 2) * D_DIM]);
        }
        __syncthreads();   // vmcnt(0) drain + barrier: tile ready

        f32x4 accP[4] = {}, accI[4] = {};
        #pragma unroll
        for (int ks = 0; ks < KSTEPS; ++ks) {
            #pragma unroll
            for (int cg = 0; cg < 4; ++cg) {
                const int rB  = cg * 16 + l16;               // B column = LDS row
                // data granule (8B) index = ks*4+quad; stored at pos = g ^ ((row&7)<<1)
                const int pos = (ks * 4 + quad) ^ ((rB & 7) << 1);
                f8x8 b = *(const f8x8*)&Bt[(size_t)rB * D_DIM + pos * 8];
                accP[cg] = __builtin_amdgcn_mfma_f32_16x16x32_fp8_fp8(Ap[ks], b, accP[cg], 0, 0, 0);
                accI[cg] = __builtin_amdgcn_mfma_f32_16x16x32_fp8_fp8(Ai[ks], b, accI[cg], 0, 0, 0);
            }
        }

        // Epilogue: zone = exp2(acc*scale + bias); one mask load feeds both
        #pragma unroll
        for (int cg = 0; cg < 4; ++cg) {
            const int j = j0 + cg * 16 + l16;
            #pragma unroll
            for (int r = 0; r < 4; ++r) {
                const float m = negmask[(size_t)lab[r] * N + j];
                float zp = exp2f(accP[cg][r] * scale + bias);
                float zi = exp2f(accI[cg][r] * scale + bias);
                denP[r] += zp; numP[r] += zp * m;
                denI[r] += zi; numI[r] += zi * m;
            }
        }
    }

    // Reduce across the 16 lanes (l16) sharing each output row, then atomicAdd
    #pragma unroll
    for (int r = 0; r < 4; r++) {
        float np = numP[r], dp = denP[r], ni = numI[r], di = denI[r];
        #pragma unroll
        for (int off = 8; off > 0; off >>= 1) {
            np += __shfl_down(np, off, 16);
            dp += __shfl_down(dp, off, 16);
            ni += __shfl_down(ni, off, 16);
            di += __shfl_down(di, off, 16);
        }
        if (l16 == 0) {
            const int row = row0 + quad * 4 + r;
            atomicAdd(&nd[row],         np);
            atomicAdd(&nd[N + row],     dp);
            atomicAdd(&nd[2 * N + row], ni);
            atomicAdd(&nd[3 * N + row], di);
        }
    }

    // ---- Last-block-done loss reduction (r8-proven; saves a dispatch) ----
    __shared__ int isLast;
    __threadfence();                         // release this block's atomics
    if (tid == 0) {
        int prev = __hip_atomic_fetch_add(ctr, 1, __ATOMIC_ACQ_REL,
                                          __HIP_MEMORY_SCOPE_AGENT);
        isLast = (prev == (int)gridDim.x - 1);
    }
    __syncthreads();
    if (isLast) {
        float s = 0.f;
        for (int i = tid; i < N; i += 256) {
            float pn  = __hip_atomic_load(&nd[i],         __ATOMIC_RELAXED, __HIP_MEMORY_SCOPE_AGENT);
            float pd  = __hip_atomic_load(&nd[N + i],     __ATOMIC_RELAXED, __HIP_MEMORY_SCOPE_AGENT);
            float in_ = __hip_atomic_load(&nd[2 * N + i], __ATOMIC_RELAXED, __HIP_MEMORY_SCOPE_AGENT);
            float id  = __hip_atomic_load(&nd[3 * N + i], __ATOMIC_RELAXED, __HIP_MEMORY_SCOPE_AGENT);
            s += (logf(pd) - logf(pn)) + (logf(id) - logf(in_));
        }
        #pragma unroll
        for (int off = 32; off > 0; off >>= 1) s += __shfl_down(s, off, 64);
        float* wss = (float*)Bt;             // LDS reuse; compute phase done
        __syncthreads();
        if ((tid & 63) == 0) wss[tid >> 6] = s;
        __syncthreads();
        if (tid == 0)
            out[0] = (wss[0] + wss[1] + wss[2] + wss[3]) / (float)N
                   - 2.0f * logf(temp);
    }
}

extern "C" void kernel_launch(void* const* d_in, const int* in_sizes, int n_in,
                              void* d_out, int out_size, void* d_ws, size_t ws_size,
                              hipStream_t stream)
{
    const float* inst     = (const float*)d_in[0];
    const float* proxy    = (const float*)d_in[1];
    const float* negmask  = (const float*)d_in[2];
    const int*   labels   = (const int*)d_in[3];
    const float* temp_p   = (const float*)d_in[4];
    const float* margin_p = (const float*)d_in[5];
    float* out = (float*)d_out;

    const int N = in_sizes[3];    // 4096 (D fixed at 512 per reference)

    unsigned char* instq  = (unsigned char*)d_ws;
    unsigned char* proxyq = instq + (size_t)N * D_DIM;
    float* nd = (float*)(proxyq + (size_t)N * D_DIM);
    int*  ctr = (int*)(nd + 4 * (size_t)N);

    normalize_rows<<<2 * N / 16, 256, 0, stream>>>(inst, proxy, instq, proxyq,
                                                   nd, ctr, N);
    fused_scores<<<(N / BM) * GRIDY, 256, 0, stream>>>(instq, proxyq, negmask,
                                                       labels, temp_p, margin_p,
                                                       nd, ctr, out, N, N / GRIDY);
}